// Round 10
// baseline (59.442 us; speedup 1.0000x reference)
//
#include <hip/hip_runtime.h>
#include <cstdint>
#include <cstddef>

// Problem constants
#define B_    32
#define N_    5023
#define F_    64
#define S_    9
#define OUT_  128
#define M_TOT (B_ * N_)        // 160736
#define K_    (S_ * F_)        // 576

// Workspace layout (bytes)
#define X_ELEMS   (B_ * N_ * F_)          // 10,287,104
#define WS_XB     0                        // bf16 x: 20,574,208 B
#define WS_WB     20574208                 // bf16 W: 147,456 B

typedef __attribute__((ext_vector_type(8))) short          bf16x8;
typedef __attribute__((ext_vector_type(4))) float          f32x4;
typedef __attribute__((ext_vector_type(8))) unsigned short u16x8;

// ---------------------------------------------------------------------------
// Fused fp32->bf16 (RNE) conversion for x and W in one grid.
// ---------------------------------------------------------------------------
__global__ void cvt_xw(const float* __restrict__ x, const float* __restrict__ W,
                       unsigned short* __restrict__ xb, unsigned short* __restrict__ Wb,
                       int nx8, int nw8) {
    const int i = blockIdx.x * blockDim.x + threadIdx.x;
    const float* src;
    unsigned short* dst;
    if (i < nx8) { src = x + (size_t)i * 8; dst = xb + (size_t)i * 8; }
    else {
        const int j = i - nx8;
        if (j >= nw8) return;
        src = W + (size_t)j * 8; dst = Wb + (size_t)j * 8;
    }
    const float4 v0 = ((const float4*)src)[0], v1 = ((const float4*)src)[1];
    const float vv[8] = {v0.x, v0.y, v0.z, v0.w, v1.x, v1.y, v1.z, v1.w};
    u16x8 r;
    #pragma unroll
    for (int k = 0; k < 8; ++k) {
        uint32_t u = __float_as_uint(vv[k]);
        u = u + 0x7fffu + ((u >> 16) & 1u);
        r[k] = (unsigned short)(u >> 16);
    }
    *(u16x8*)dst = r;
}

// ---------------------------------------------------------------------------
// Main MFMA kernel, round-10: 128 rows x 128 cols per block, 8 waves (4x2,
// wave tile 32x64, 2x4 frags of mfma_f32_16x16x32_bf16).
//
// K-step = 32 (18 steps), LDS = 3 x {A[128][32], W[128][32]} = 48 KB
// -> 3 blocks/CU (24 waves). Depth-2 pipeline with COUNTED vmcnt (T3/T4):
//   step t: s_waitcnt vmcnt(2)   // retire stage(t), issued 2 steps ago
//           __syncthreads()      // tile t complete block-wide
//           COMPUTE(buf t%3)
//           STAGE(buf (t+2)%3, t+2)
// vmcnt never drains to 0 in the loop; each stage has ~2 compute-steps of
// latency slack. Barrier-t also orders stage(t+2) after all compute(t-1)
// (WAR on the recycled buffer).
//
// Swizzle (64-B rows, 4 x 16-B chunks): phys = logical ^ ((row>>1)&3),
// applied on the staging global source (LDS dest linear, m173) and on the
// ds_read address. 2-way within each 16-lane phase group => conflict-free.
// ---------------------------------------------------------------------------
__global__ __launch_bounds__(512, 6)
void spiral_mfma(const unsigned short* __restrict__ xb,
                 const void* __restrict__ adj,
                 const unsigned short* __restrict__ Wb,
                 const float* __restrict__ bias,
                 float* __restrict__ out) {
    __shared__ unsigned short Alds[3][128 * 32];   // 24 KB
    __shared__ unsigned short Wlds[3][128 * 32];   // 24 KB

    const int tid = threadIdx.x;
    const int l   = tid & 63;
    const int w   = tid >> 6;                      // 0..7
    const int wr  = w >> 1;                        // compute row-group 0..3
    const int wc  = w & 1;                         // compute col-half 0..1

    // Uniform dtype probe: odd 32-bit words of the first 8 int64 slots are
    // all zero iff adj is int64 (indices < 2^31). Scalar loads, broadcast.
    const int* aw = (const int*)adj;
    const int pv = aw[1] | aw[3] | aw[5] | aw[7] | aw[9] | aw[11] | aw[13] | aw[15];
    const int sh = (pv == 0) ? 3 : 2;              // byte shift per element
    const char* adjp = (const char*)adj;

    // XCD-chunked bijective swizzle: 1256 = 8 * 157.
    const int bid = blockIdx.x;
    const int nb  = (bid & 7) * 157 + (bid >> 3);
    const int m0  = nb * 128;

    // Staging assignment: each thread stages ONE A row and ONE W row per
    // step: row-in-block = w*16 + (l>>2), phys chunk = l&3.
    // Source logical chunk (involution): lc = (l&3) ^ ((l>>3)&3).
    const int srow = w * 16 + (l >> 2);
    const int lc   = (l & 3) ^ ((l >> 3) & 3);

    int r = m0 + srow;
    if (r >= M_TOT) r = M_TOT - 1;
    const uint32_t xr = (uint32_t)(r / N_) * (N_ * F_);

    // Preload all 9 spiral indices for this thread's staging row.
    int idxv[S_];
    {
        const int base = r * S_;
        #pragma unroll
        for (int s = 0; s < S_; ++s)
            idxv[s] = *(const int*)(adjp + ((size_t)(base + s) << sh));
    }

    const unsigned short* wsrc_base = Wb + (size_t)srow * K_ + lc * 8;

    f32x4 acc[2][4];
    #pragma unroll
    for (int mi = 0; mi < 2; ++mi)
        #pragma unroll
        for (int ni = 0; ni < 4; ++ni) {
            acc[mi][ni][0] = 0.f; acc[mi][ni][1] = 0.f;
            acc[mi][ni][2] = 0.f; acc[mi][ni][3] = 0.f;
        }

    #define STAGE(buf_, t_)                                                     \
        do {                                                                    \
            const int s_ = (t_) >> 1, hf_ = (t_) & 1;                           \
            const unsigned short* srcA = xb + xr +                              \
                (uint32_t)idxv[s_] * F_ + hf_ * 32 + lc * 8;                    \
            __builtin_amdgcn_global_load_lds(                                   \
                (const __attribute__((address_space(1))) void*)srcA,            \
                (__attribute__((address_space(3))) void*)&Alds[(buf_)][w * 512],\
                16, 0, 0);                                                      \
            const unsigned short* srcW = wsrc_base + s_ * F_ + hf_ * 32;        \
            __builtin_amdgcn_global_load_lds(                                   \
                (const __attribute__((address_space(1))) void*)srcW,            \
                (__attribute__((address_space(3))) void*)&Wlds[(buf_)][w * 512],\
                16, 0, 0);                                                      \
        } while (0)

    // Frag read: row = base + (l&15), logical chunk = l>>4,
    // phys = (l>>4) ^ ((l>>1)&3)  (row bases are multiples of 8).
    const int phys8 = (((l >> 4) ^ ((l >> 1) & 3))) * 8;   // elem offset
    const int arow0 = (wr * 32 + (l & 15)) * 32 + phys8;
    const int brow0 = (wc * 64 + (l & 15)) * 32 + phys8;

    #define COMPUTE(buf_)                                                       \
        do {                                                                    \
            bf16x8 av[2], bv[4];                                                \
            _Pragma("unroll")                                                   \
            for (int mi = 0; mi < 2; ++mi)                                      \
                av[mi] = *(const bf16x8*)&Alds[(buf_)][arow0 + mi * 512];       \
            _Pragma("unroll")                                                   \
            for (int ni = 0; ni < 4; ++ni)                                      \
                bv[ni] = *(const bf16x8*)&Wlds[(buf_)][brow0 + ni * 512];       \
            __builtin_amdgcn_s_setprio(1);                                      \
            _Pragma("unroll")                                                   \
            for (int mi = 0; mi < 2; ++mi)                                      \
                _Pragma("unroll")                                               \
                for (int ni = 0; ni < 4; ++ni)                                  \
                    acc[mi][ni] = __builtin_amdgcn_mfma_f32_16x16x32_bf16(      \
                        av[mi], bv[ni], acc[mi][ni], 0, 0, 0);                  \
            __builtin_amdgcn_s_setprio(0);                                      \
        } while (0)

    // Prologue: ensure idx loads are retired so loop vmcnt counts are exact.
    __builtin_amdgcn_sched_barrier(0);
    asm volatile("s_waitcnt vmcnt(0)" ::: "memory");
    __builtin_amdgcn_sched_barrier(0);

    STAGE(0, 0);
    STAGE(1, 1);

    // 18 steps, counted waits: vmcnt(2) retires the stage issued 2 steps ago
    // (2 insts/stage/thread; outstanding before wait = 4, after = 2).
    #pragma unroll
    for (int t = 0; t < 18; ++t) {
        if (t < 17) {
            asm volatile("s_waitcnt vmcnt(2)" ::: "memory");
        } else {
            asm volatile("s_waitcnt vmcnt(0)" ::: "memory");
        }
        __builtin_amdgcn_sched_barrier(0);
        __syncthreads();
        COMPUTE(t % 3);
        if (t + 2 < 18) STAGE((t + 2) % 3, t + 2);
    }

    #undef STAGE
    #undef COMPUTE

    // Epilogue: bias + fast ELU + row-mask + non-temporal stores.
    // C/D: col = l&15, row = (l>>4)*4 + j per 16x16 frag.
    float bs[4];
    #pragma unroll
    for (int ni = 0; ni < 4; ++ni) bs[ni] = bias[wc * 64 + ni * 16 + (l & 15)];

    const int rb = m0 + wr * 32 + (l >> 4) * 4;
    const int cb = wc * 64 + (l & 15);
    #pragma unroll
    for (int mi = 0; mi < 2; ++mi) {
        #pragma unroll
        for (int j = 0; j < 4; ++j) {
            const int m = rb + mi * 16 + j;
            if (m < M_TOT) {
                const bool z = ((m % N_) == (N_ - 1));
                float* orow = out + (size_t)m * OUT_ + cb;
                #pragma unroll
                for (int ni = 0; ni < 4; ++ni) {
                    float v = acc[mi][ni][j] + bs[ni];
                    const float e = __expf(v) - 1.0f;   // fast ELU
                    v = v > 0.f ? v : e;
                    if (z) v = 0.f;
                    __builtin_nontemporal_store(v, &orow[ni * 16]);
                }
            }
        }
    }
}

extern "C" void kernel_launch(void* const* d_in, const int* in_sizes, int n_in,
                              void* d_out, int out_size, void* d_ws, size_t ws_size,
                              hipStream_t stream) {
    const float* x    = (const float*)d_in[0];
    const void*  adj  = d_in[1];
    const float* W    = (const float*)d_in[2];
    const float* bias = (const float*)d_in[3];
    float* out        = (float*)d_out;

    char* ws = (char*)d_ws;
    unsigned short* xb = (unsigned short*)(ws + WS_XB);
    unsigned short* Wb = (unsigned short*)(ws + WS_WB);

    const int nx8 = X_ELEMS / 8;          // 1,285,888
    const int nw8 = (OUT_ * K_) / 8;      // 9,216
    cvt_xw<<<(nx8 + nw8 + 255) / 256, 256, 0, stream>>>(x, W, xb, Wb, nx8, nw8);

    const int grid = (M_TOT + 127) / 128; // 1256 = 8 * 157
    spiral_mfma<<<grid, 512, 0, stream>>>(xb, adj, Wb, bias, out);
}